// Round 4
// baseline (259.204 us; speedup 1.0000x reference)
//
#include <hip/hip_runtime.h>

// SSIM loss, fused. fp32 [16,3,512,512] x2 -> scalar.
// Tile 64x16 outputs per 256-thread block. Phase 1: horizontal 7-tap for 22
// rows x 64 cols, 5 channels (x,y,xx,yy,xy), loads straight from global
// (3 guarded aligned float4 per array), results to LDS (b128 writes).
// Phase 2: vertical 7-tap from LDS (b128 reads) + SSIM map + block reduce.
// Mean folded in via one atomicAdd per block.

#define IMG 512
#define TW 64
#define TH 16
#define HR 22                    // TH + 6 halo rows
#define HSTRIDE 68               // pad 64->68: +4 banks/row rotation, 16B aligned
#define NPLANES 48
#define NBLK ((IMG / TW) * (IMG / TH) * NPLANES)  // 8*32*48 = 12288
#define SSIM_C1 1.0e-4f
#define SSIM_C2 9.0e-4f

__device__ __constant__ float c_gw[7] = {
    0.03663284536f, 0.11128076166f, 0.21674531251f, 0.27068216094f,
    0.21674531251f, 0.11128076166f, 0.03663284536f};

__global__ __launch_bounds__(256) void ssim_main(
    const float* __restrict__ X, const float* __restrict__ Y,
    float* __restrict__ out) {
  __shared__ float hs[5][HR][HSTRIDE];

  const int tid = threadIdx.x;
  const int x0 = blockIdx.x * TW;
  const int row0 = blockIdx.y * TH - 3;
  const int plane = blockIdx.z;
  const float* __restrict__ xp = X + (size_t)plane * IMG * IMG;
  const float* __restrict__ yp = Y + (size_t)plane * IMG * IMG;

  const float g0 = c_gw[0], g1 = c_gw[1], g2 = c_gw[2], g3 = c_gw[3];
  const float gw[7] = {g0, g1, g2, g3, g2, g1, g0};

  // ---- Phase 1: horizontal pass, 22 rows x 16 col-groups of 4 px ----
  for (int i = tid; i < HR * 16; i += 256) {
    const int r = i >> 4, cg = i & 15;
    const int gy = row0 + r;
    const int c4 = cg * 4;                 // local col of first output px
    const int gb = x0 + c4 - 4;            // aligned global load base
    const bool rowok = (unsigned)gy < (unsigned)IMG;
    const bool ok0 = (gb >= 0);
    const bool ok2 = (gb + 11 < IMG);

    const float4 z4 = make_float4(0.f, 0.f, 0.f, 0.f);
    float4 a0 = z4, a1 = z4, a2 = z4, b0 = z4, b1 = z4, b2 = z4;
    if (rowok) {
      const float* xr = xp + (size_t)gy * IMG + gb;
      const float* yr = yp + (size_t)gy * IMG + gb;
      if (ok0) a0 = *(const float4*)(xr);
      a1 = *(const float4*)(xr + 4);
      if (ok2) a2 = *(const float4*)(xr + 8);
      if (ok0) b0 = *(const float4*)(yr);
      b1 = *(const float4*)(yr + 4);
      if (ok2) b2 = *(const float4*)(yr + 8);
    }
    const float wx[12] = {a0.x, a0.y, a0.z, a0.w, a1.x, a1.y,
                          a1.z, a1.w, a2.x, a2.y, a2.z, a2.w};
    const float wy[12] = {b0.x, b0.y, b0.z, b0.w, b1.x, b1.y,
                          b1.z, b1.w, b2.x, b2.y, b2.z, b2.w};

    float h[5][4];
#pragma unroll
    for (int ch = 0; ch < 5; ++ch)
#pragma unroll
      for (int p = 0; p < 4; ++p) h[ch][p] = 0.f;
#pragma unroll
    for (int k = 0; k < 7; ++k) {
      const float g = gw[k];
#pragma unroll
      for (int p = 0; p < 4; ++p) {
        const float xv = wx[1 + p + k];
        const float yv = wy[1 + p + k];
        const float t1 = g * xv;
        const float t2 = g * yv;
        h[0][p] += t1;
        h[1][p] += t2;
        h[2][p] = __builtin_fmaf(t1, xv, h[2][p]);
        h[3][p] = __builtin_fmaf(t2, yv, h[3][p]);
        h[4][p] = __builtin_fmaf(t1, yv, h[4][p]);
      }
    }
#pragma unroll
    for (int ch = 0; ch < 5; ++ch) {
      *(float4*)&hs[ch][r][c4] =
          make_float4(h[ch][0], h[ch][1], h[ch][2], h[ch][3]);
    }
  }
  __syncthreads();

  // ---- Phase 2: vertical pass + SSIM, 4 px per thread ----
  const int orow = tid >> 4;              // 0..15
  const int c4 = (tid & 15) * 4;          // 0..60

  float m1[4] = {0.f, 0.f, 0.f, 0.f}, m2[4] = {0.f, 0.f, 0.f, 0.f};
  float exx[4] = {0.f, 0.f, 0.f, 0.f}, eyy[4] = {0.f, 0.f, 0.f, 0.f};
  float exy[4] = {0.f, 0.f, 0.f, 0.f};
#pragma unroll
  for (int k = 0; k < 7; ++k) {
    const float g = gw[k];
    const float4 v1 = *(const float4*)&hs[0][orow + k][c4];
    const float4 v2 = *(const float4*)&hs[1][orow + k][c4];
    const float4 v3 = *(const float4*)&hs[2][orow + k][c4];
    const float4 v4 = *(const float4*)&hs[3][orow + k][c4];
    const float4 v5 = *(const float4*)&hs[4][orow + k][c4];
    const float a1[4] = {v1.x, v1.y, v1.z, v1.w};
    const float a2[4] = {v2.x, v2.y, v2.z, v2.w};
    const float a3[4] = {v3.x, v3.y, v3.z, v3.w};
    const float a4[4] = {v4.x, v4.y, v4.z, v4.w};
    const float a5[4] = {v5.x, v5.y, v5.z, v5.w};
#pragma unroll
    for (int p = 0; p < 4; ++p) {
      m1[p] = __builtin_fmaf(g, a1[p], m1[p]);
      m2[p] = __builtin_fmaf(g, a2[p], m2[p]);
      exx[p] = __builtin_fmaf(g, a3[p], exx[p]);
      eyy[p] = __builtin_fmaf(g, a4[p], eyy[p]);
      exy[p] = __builtin_fmaf(g, a5[p], exy[p]);
    }
  }

  float ssim_acc = 0.f;
#pragma unroll
  for (int p = 0; p < 4; ++p) {
    const float mu1 = m1[p], mu2 = m2[p];
    const float mu1sq = mu1 * mu1;
    const float mu2sq = mu2 * mu2;
    const float mu12 = mu1 * mu2;
    const float sig1 = exx[p] - mu1sq;
    const float sig2 = eyy[p] - mu2sq;
    const float sig12 = exy[p] - mu12;
    const float num = (2.f * mu12 + SSIM_C1) * (2.f * sig12 + SSIM_C2);
    const float den = (mu1sq + mu2sq + SSIM_C1) * (sig1 + sig2 + SSIM_C2);
    ssim_acc += num * __builtin_amdgcn_rcpf(den);
  }

  // ---- Block reduction (4 waves) + atomic fold-in ----
#pragma unroll
  for (int off = 32; off > 0; off >>= 1)
    ssim_acc += __shfl_down(ssim_acc, off, 64);
  __shared__ float wsum[4];
  if ((tid & 63) == 0) wsum[tid >> 6] = ssim_acc;
  __syncthreads();
  if (tid == 0) {
    const float s = wsum[0] + wsum[1] + wsum[2] + wsum[3];
    const float inv_n = 1.0f / (48.0f * 512.0f * 512.0f);
    atomicAdd(out, 1.0f / (float)NBLK - s * inv_n);
  }
}

extern "C" void kernel_launch(void* const* d_in, const int* in_sizes, int n_in,
                              void* d_out, int out_size, void* d_ws, size_t ws_size,
                              hipStream_t stream) {
  const float* enhanced = (const float*)d_in[0];
  const float* target = (const float*)d_in[1];
  float* out = (float*)d_out;

  hipMemsetAsync(out, 0, sizeof(float), stream);
  dim3 grid(IMG / TW, IMG / TH, NPLANES);   // 8 x 32 x 48 = 12288
  ssim_main<<<grid, dim3(256), 0, stream>>>(enhanced, target, out);
}